// Round 5
// baseline (523.977 us; speedup 1.0000x reference)
//
#include <hip/hip_runtime.h>

#define Kk 8
#define SIZEk 64
#define PDd 256
#define EDd 768
#define Nn 197
#define NPROD 64         // producer (keys/KW/ksim) blocks (first dispatched)
#define NR 512           // route blocks, ONE bz each
#define ED4 192          // 768/4
#define PD4 64           // 256/4
#define TOT4 (Nn * ED4)  // 37824 float4 per bz
#define JFULL (TOT4 / 256)          // 147 full 256-wide rounds
#define JMAIN (JFULL - (JFULL % 6)) // 144 (class offset re-aligns to 0)
#define OUT_LOSS ((size_t)32 * 128 * EDd)   // 3145728: ps_loss slot in d_out
#define LOSS_SCALE (1.0f / 32.0f)           // F/BZ = 16/512
#define MAGIC 0x5A17EC0Du                   // != 0xAAAAAAAA poison, != 0

__device__ __forceinline__ void acc4(float4& s, float4 a) {
    s.x += a.x; s.y += a.y; s.z += a.z; s.w += a.w;
}

// ONE kernel, ONE launch (R0-proven fastest structure), 576 blocks.
//  blocks 0..63   producers: keys[s]=l2norm(pv[s]); KW[s]=keys[s]@Wout^T; release
//                 slots[s]; ksim row s after acquiring all slots. First 64
//                 dispatched => co-resident => mutual spin safe (R0/R2-proven).
//  blocks 64..575 route blocks, one bz each: contiguous 591 KB x-read (3-class
//                 static-reg accumulator, R4-verified), LDS combine, query,
//                 THEN poll producer slots (R0-proven placement: producers are
//                 long done => ~0 spin; no R3 spin-storm), top-8, recon, gather.
// vs R0: 2x blocks (1.25 -> 2.25 blocks/CU), half the per-block x footprint
// (halves the scheduling tail), same low-VGPR unroll discipline (R1's deep
// unroll regressed).
__global__ __launch_bounds__(256, 2) void k_all(const float4* __restrict__ x,
                                                const float* __restrict__ Win,
                                                const float* __restrict__ Wout,
                                                const float* __restrict__ pv,
                                                float* __restrict__ keys,
                                                float* __restrict__ KW,
                                                unsigned* __restrict__ slots,
                                                float* __restrict__ out) {
    int blk = blockIdx.x, t = threadIdx.x;

    if (blk < NPROD) {
        // ================= producer block s =================
        __shared__ float ks[PDd];
        __shared__ float redp[4];
        __shared__ float s_norm;
        int s = blk;
        float v  = pv[(size_t)s * PDd + t];
        float sq = v * v;
        for (int o = 32; o > 0; o >>= 1) sq += __shfl_down(sq, o);
        if ((t & 63) == 0) redp[t >> 6] = sq;
        __syncthreads();
        if (t == 0) s_norm = fmaxf(sqrtf(redp[0] + redp[1] + redp[2] + redp[3]), 1e-12f);
        __syncthreads();
        float kv = v / s_norm;
        ks[t] = kv;
        keys[(size_t)s * PDd + t] = kv;
        __syncthreads();

        // KW row s: 768 outputs, 3 per thread
        for (int r = 0; r < 3; r++) {
            int e = t + 256 * r;
            const float4* w  = (const float4*)(Wout + (size_t)e * PDd);
            const float4* k4 = (const float4*)ks;
            float d = 0.f;
            for (int i = 0; i < PD4; i++) {
                float4 wv = w[i]; float4 kvv = k4[i];
                d += wv.x * kvv.x + wv.y * kvv.y + wv.z * kvv.z + wv.w * kvv.w;
            }
            KW[(size_t)s * EDd + e] = d;
        }
        if (s == 0 && t == 0) out[OUT_LOSS] = 0.0f;   // ordered before slot-0 release
        __syncthreads();   // vmcnt(0) drain before barrier: stores visible
        if (t == 0)
            __hip_atomic_store(&slots[s], MAGIC, __ATOMIC_RELEASE, __HIP_MEMORY_SCOPE_AGENT);

        // ---- ksim row s (needs ALL keys; producers co-resident => ~0 spin) --
        if (t < SIZEk) {
            while (__hip_atomic_load(&slots[t], __ATOMIC_ACQUIRE, __HIP_MEMORY_SCOPE_AGENT)
                   != MAGIC)
                __builtin_amdgcn_s_sleep(8);
        }
        __syncthreads();
        if (t < SIZEk) {
            const float4* a = (const float4*)(keys + (size_t)s * PDd);
            const float4* b = (const float4*)(keys + (size_t)t * PDd);
            float d = 0.f;
            for (int c = 0; c < PD4; c++) {
                float4 av = a[c], bv = b[c];
                d += av.x * bv.x + av.y * bv.y + av.z * bv.z + av.w * bv.w;
            }
            float vv = fabsf(d - (s == t ? 1.0f : 0.0f));
            for (int o = 32; o > 0; o >>= 1) vv += __shfl_down(vv, o);
            if (t == 0) atomicAdd(out + OUT_LOSS, vv * LOSS_SCALE);
        }
        return;
    }

    // ================= route block: ONE bz =================
    __shared__ float4 part[4][ED4];  // 12 KB: per-wave class partials
    __shared__ float4 xs4[ED4];      // xf row (192 float4)
    __shared__ float4 qs4[PD4];      // normalized query row (256 floats)
    __shared__ int    s_idx[Kk];
    __shared__ float  s_sim[Kk];
    __shared__ float  red[4];
    int bz = blk - NPROD;

    // ---- phase 1: contiguous flat read of bz's 37824 float4; class of flat
    //      index f = f%192 cycles 0,64,128 per +256 => 3 static reg slots. ----
    {
        const float4* base = x + (size_t)bz * TOT4;
        float4 a0 = make_float4(0.f, 0.f, 0.f, 0.f);
        float4 a1 = a0, a2 = a0;
        int j = 0;
        for (; j < JMAIN; j += 6) {              // 6 independent 1KB wave-loads
            const float4* p = base + (size_t)j * 256 + t;
            float4 v0 = p[0 * 256], v1 = p[1 * 256], v2 = p[2 * 256];
            float4 v3 = p[3 * 256], v4 = p[4 * 256], v5 = p[5 * 256];
            acc4(a0, v0); acc4(a1, v1); acc4(a2, v2);
            acc4(a0, v3); acc4(a1, v4); acc4(a2, v5);
        }
        // remainder: JMAIN*256 % 192 == 0 => classes resume at slot 0; 4 guarded
        // rounds cover j = 144..147 (last partial: t < 192).
        int f = JMAIN * 256 + t;
        if (f < TOT4) acc4(a0, base[f]); f += 256;
        if (f < TOT4) acc4(a1, base[f]); f += 256;
        if (f < TOT4) acc4(a2, base[f]); f += 256;
        if (f < TOT4) acc4(a0, base[f]);

        // LDS combine: wave k's threads cover classes {t%192,(t+64)%192,(t+128)%192}
        // = all 192 exactly once per wave => part[k][*] written once each.
        int k  = t >> 6;
        int c0 = t % ED4;
        int c1 = (t + 64) % ED4;
        int c2 = (t + 128) % ED4;
        part[k][c0] = a0;
        part[k][c1] = a1;
        part[k][c2] = a2;
    }
    __syncthreads();
    if (t < ED4) {
        float4 s = part[0][t];
        acc4(s, part[1][t]); acc4(s, part[2][t]); acc4(s, part[3][t]);
        const float inv = 1.0f / (float)Nn;
        xs4[t] = make_float4(s.x * inv, s.y * inv, s.z * inv, s.w * inv);
    }
    __syncthreads();

    // ---- phase 2: query dim t (256 dims, one 768-dot each) ----
    float qv;
    {
        const float4* w = (const float4*)Win + (size_t)t * ED4;
        float da = 0.f, db = 0.f;
        for (int i = 0; i < ED4; i += 2) {       // split accumulators
            float4 w0 = w[i], w1 = w[i + 1];
            float4 u0 = xs4[i], u1 = xs4[i + 1];
            da += w0.x * u0.x + w0.y * u0.y + w0.z * u0.z + w0.w * u0.w;
            db += w1.x * u1.x + w1.y * u1.y + w1.z * u1.z + w1.w * u1.w;
        }
        float d0 = da + db;
        float sq = d0 * d0;
        for (int o = 32; o > 0; o >>= 1) sq += __shfl_down(sq, o);
        if ((t & 63) == 0) red[t >> 6] = sq;
        __syncthreads();
        float n0 = fmaxf(sqrtf(red[0] + red[1] + red[2] + red[3]), 1e-12f);
        qv = d0 / n0;
        ((float*)qs4)[t] = qv;
    }

    // ---- acquire keys/KW (R0-proven placement: after the heavy phases) ----
    if (t < SIZEk) {
        while (__hip_atomic_load(&slots[t], __ATOMIC_ACQUIRE, __HIP_MEMORY_SCOPE_AGENT)
               != MAGIC)
            __builtin_amdgcn_s_sleep(8);
    }
    __syncthreads();   // also orders qs4 writes before phase-3 reads

    // ---- phase 3: sim + top-8 on wave 0 (lane <-> key) ----
    if (t < SIZEk) {
        int lane = t;
        const float4* kr = (const float4*)(keys + (size_t)lane * PDd);
        float d = 0.f;
        for (int c = 0; c < PD4; c++) {
            float4 a = kr[c], b = qs4[c];
            d += a.x * b.x + a.y * b.y + a.z * b.z + a.w * b.w;
        }
        float v = d;
        for (int k = 0; k < Kk; k++) {
            float mv = v; int mi = lane;
            for (int o = 32; o > 0; o >>= 1) {
                float ov = __shfl_xor(mv, o);
                int   oi = __shfl_xor(mi, o);
                if (ov > mv || (ov == mv && oi < mi)) { mv = ov; mi = oi; }
            }
            if (lane == 0) { s_idx[k] = mi; s_sim[k] = mv; }
            if (lane == mi) v = -3e38f;  // remove winner (tie -> lowest idx)
        }
    }
    __syncthreads();

    // ---- phase 4: recon + diff (thread t == dim) ----
    {
        float r = 0.f;
        for (int k = 0; k < Kk; k++)
            r += s_sim[k] * keys[(size_t)s_idx[k] * PDd + t];
        float e = r - qv;
        float sq = e * e;
        for (int o = 32; o > 0; o >>= 1) sq += __shfl_down(sq, o);
        if ((t & 63) == 0) red[t >> 6] = sq;
        __syncthreads();
        if (t == 0) atomicAdd(out + OUT_LOSS,
                              (red[0] + red[1] + red[2] + red[3]) * LOSS_SCALE);
    }

    // ---- phase 5: 8 contiguous out rows (bz*K .. bz*K+7) = KW[idx] gather ----
    float4* orow = (float4*)out + (size_t)bz * Kk * ED4;
    for (int i = t; i < Kk * ED4; i += 256) {
        int which = i / ED4;         // 0..7
        int e4    = i - which * ED4;
        int idx   = s_idx[which];
        orow[i] = ((const float4*)(KW + (size_t)idx * EDd))[e4];
    }
}

extern "C" void kernel_launch(void* const* d_in, const int* in_sizes, int n_in,
                              void* d_out, int out_size, void* d_ws, size_t ws_size,
                              hipStream_t stream) {
    const float* x    = (const float*)d_in[0];   // [32, 16*197, 768]
    const float* Win  = (const float*)d_in[1];   // [256, 768]
    const float* Wout = (const float*)d_in[2];   // [768, 256]
    const float* pv   = (const float*)d_in[3];   // [64, 1, 256]
    float* out = (float*)d_out;                  // [32,128,768] ++ [1]
    float* ws  = (float*)d_ws;

    float*    keys  = ws;                        // 64*256 = 16384 floats
    float*    KW    = ws + 16384;                // 64*768 = 49152 floats
    unsigned* slots = (unsigned*)(ws + 65536);   // 64 flags (poisoned != MAGIC)

    k_all<<<NPROD + NR, 256, 0, stream>>>((const float4*)x, Win, Wout, pv,
                                          keys, KW, slots, out);
}